// Round 6
// baseline (300.587 us; speedup 1.0000x reference)
//
#include <hip/hip_runtime.h>
#include <hip/hip_bf16.h>

#define B_ 2048
#define N_ 8
#define D_ 1024
#define V_ 4096
#define LN_EPS_ 1e-5f

typedef __bf16 bf16x8 __attribute__((ext_vector_type(8)));
typedef float f32x16 __attribute__((ext_vector_type(16)));

static __device__ __forceinline__ unsigned short f2bf(float x) {
    union { float f; unsigned int u; } v;
    v.f = x;
    unsigned int r = v.u + 0x7fffu + ((v.u >> 16) & 1u);
    return (unsigned short)(r >> 16);
}

// ---------------------------------------------------------------------------
// prep: fused  (a) W_pred (N,D,V) f32 -> Wt (N,V,D) bf16   [blocks 2048..10239]
//              (b) gather+cumsum+LN+GELU -> H (N,B,D) bf16 [blocks 0..2047]
// ---------------------------------------------------------------------------
__global__ __launch_bounds__(256) void prep(const float* __restrict__ ie,
                                            const int* __restrict__ feats,
                                            const float* __restrict__ emb,
                                            const float* __restrict__ gamma,
                                            const float* __restrict__ beta,
                                            const float* __restrict__ W,
                                            unsigned short* __restrict__ H,
                                            unsigned short* __restrict__ Wt) {
    const int bid = blockIdx.x;
    const int t = threadIdx.x;

    if (bid >= 2048) {
        __shared__ unsigned short tile[64][65];
        const int w  = bid - 2048;
        const int v0 = (w & 63) * 64;
        const int d0 = ((w >> 6) & 15) * 64;
        const int n  = w >> 10;
        const int tx = t & 15, ty = t >> 4;
#pragma unroll
        for (int i = 0; i < 4; ++i) {
            const int d = ty + i * 16;
            const float4 w4 = *(const float4*)&W[((size_t)n * D_ + d0 + d) * V_ + v0 + tx * 4];
            tile[d][tx * 4 + 0] = f2bf(w4.x);
            tile[d][tx * 4 + 1] = f2bf(w4.y);
            tile[d][tx * 4 + 2] = f2bf(w4.z);
            tile[d][tx * 4 + 3] = f2bf(w4.w);
        }
        __syncthreads();
#pragma unroll
        for (int i = 0; i < 4; ++i) {
            const int v = ty + i * 16;
            ushort4 pk;
            pk.x = tile[tx * 4 + 0][v];
            pk.y = tile[tx * 4 + 1][v];
            pk.z = tile[tx * 4 + 2][v];
            pk.w = tile[tx * 4 + 3][v];
            *reinterpret_cast<ushort4*>(&Wt[((size_t)n * V_ + v0 + v) * D_ + d0 + tx * 4]) = pk;
        }
    } else {
        __shared__ float redS[4], redQ[4];
        const int b = bid;
        const int d0 = t * 4;
        const int lane = t & 63, wid = t >> 6;

        float4 s  = *(const float4*)&ie[(size_t)b * D_ + d0];
        const float4 g4 = *(const float4*)&gamma[d0];
        const float4 be4 = *(const float4*)&beta[d0];

        int fc[N_];
#pragma unroll
        for (int n = 0; n < N_; ++n) fc[n] = feats[b * N_ + n];

#pragma unroll
        for (int n = 0; n < N_; ++n) {
            float ls = s.x + s.y + s.z + s.w;
            float lq = s.x * s.x + s.y * s.y + s.z * s.z + s.w * s.w;
#pragma unroll
            for (int off = 32; off > 0; off >>= 1) {
                ls += __shfl_down(ls, off, 64);
                lq += __shfl_down(lq, off, 64);
            }
            if (lane == 0) { redS[wid] = ls; redQ[wid] = lq; }
            __syncthreads();
            const float tot  = redS[0] + redS[1] + redS[2] + redS[3];
            const float totq = redQ[0] + redQ[1] + redQ[2] + redQ[3];
            __syncthreads();

            const float mu   = tot * (1.0f / D_);
            const float var  = totq * (1.0f / D_) - mu * mu;
            const float rstd = rsqrtf(var + LN_EPS_);

            float h0 = (s.x - mu) * rstd * g4.x + be4.x;
            float h1 = (s.y - mu) * rstd * g4.y + be4.y;
            float h2 = (s.z - mu) * rstd * g4.z + be4.z;
            float h3 = (s.w - mu) * rstd * g4.w + be4.w;
            h0 = 0.5f * h0 * (1.0f + erff(h0 * 0.70710678f));
            h1 = 0.5f * h1 * (1.0f + erff(h1 * 0.70710678f));
            h2 = 0.5f * h2 * (1.0f + erff(h2 * 0.70710678f));
            h3 = 0.5f * h3 * (1.0f + erff(h3 * 0.70710678f));

            ushort4 pk;
            pk.x = f2bf(h0); pk.y = f2bf(h1); pk.z = f2bf(h2); pk.w = f2bf(h3);
            *reinterpret_cast<ushort4*>(&H[((size_t)n * B_ + b) * D_ + d0]) = pk;

            const float4 e = *(const float4*)&emb[((size_t)n * V_ + fc[n]) * (size_t)D_ + d0];
            s.x += e.x; s.y += e.y; s.z += e.z; s.w += e.w;
        }
    }
}

// ---------------------------------------------------------------------------
// gemmp: 256x256 tile, BK=64, 8 waves (2x4, wave-tile 128x64), 32x32x16 MFMA.
// Grid=256 (1 block/CU), persistent 4 jobs (vt = vtg*4+jb), 64 continuous
// K-steps. Register staging (global->reg->LDS) into [s-plane][row^m] layout:
//   granule (r,s) at addr16 = s*256 + (r ^ ((s&3)<<3))   [per 64KB buffer]
// -> global loads 128B-coalesced/8 lanes, ds_write = 2-cover (conflict-free),
//    ds_read_b128 of 32-row fragments = permuted 512B windows (conflict-free).
// Per step: 1 lgkmcnt + 1 barrier + 1 vmcnt(0); loads for step g+2 issued at
// step g (one full step of flight > HBM latency). 2 LDS buffers x 64KB.
// ---------------------------------------------------------------------------
#define MF32(a, b, c) __builtin_amdgcn_mfma_f32_32x32x16_bf16((a), (b), (c), 0, 0, 0)

#define GLOADS(G2) { \
    const unsigned short* pa = Abase + ((G2) & 15) * 64; \
    const unsigned short* pb = Bb0 + (size_t)((G2) >> 4) * (256 * D_) + ((G2) & 15) * 64; \
    ra0 = *(const float4*)(pa); \
    ra1 = *(const float4*)(pa +  64 * D_); \
    ra2 = *(const float4*)(pa + 128 * D_); \
    ra3 = *(const float4*)(pa + 192 * D_); \
    rb0 = *(const float4*)(pb); \
    rb1 = *(const float4*)(pb +  64 * D_); \
    rb2 = *(const float4*)(pb + 128 * D_); \
    rb3 = *(const float4*)(pb + 192 * D_); \
}

#define DSWRITES(BN) { \
    char* wp = lds + (BN) + wby; \
    *(float4*)(wp)         = ra0; \
    *(float4*)(wp + 1024)  = ra1; \
    *(float4*)(wp + 2048)  = ra2; \
    *(float4*)(wp + 3072)  = ra3; \
    *(float4*)(wp + 32768) = rb0; \
    *(float4*)(wp + 33792) = rb1; \
    *(float4*)(wp + 34816) = rb2; \
    *(float4*)(wp + 35840) = rb3; \
}

#define COMPUTE(BC) { \
    _Pragma("unroll") for (int kk = 0; kk < 4; ++kk) { \
        const char* rp = lds + (BC); \
        bf16x8 b0 = *(const bf16x8*)(rp + CBb[kk]); \
        bf16x8 b1 = *(const bf16x8*)(rp + CBb[kk] + 512); \
        bf16x8 a0 = *(const bf16x8*)(rp + CAb[kk]); \
        bf16x8 a1 = *(const bf16x8*)(rp + CAb[kk] + 512); \
        bf16x8 a2 = *(const bf16x8*)(rp + CAb[kk] + 1024); \
        bf16x8 a3 = *(const bf16x8*)(rp + CAb[kk] + 1536); \
        __builtin_amdgcn_s_setprio(1); \
        acc[0][0] = MF32(a0, b0, acc[0][0]); acc[0][1] = MF32(a0, b1, acc[0][1]); \
        acc[1][0] = MF32(a1, b0, acc[1][0]); acc[1][1] = MF32(a1, b1, acc[1][1]); \
        acc[2][0] = MF32(a2, b0, acc[2][0]); acc[2][1] = MF32(a2, b1, acc[2][1]); \
        acc[3][0] = MF32(a3, b0, acc[3][0]); acc[3][1] = MF32(a3, b1, acc[3][1]); \
        __builtin_amdgcn_s_setprio(0); \
    } \
}

#define STEP(BC, BN, G, DO_W, DO_I) { \
    asm volatile("s_waitcnt lgkmcnt(0)" ::: "memory"); \
    __builtin_amdgcn_s_barrier(); \
    asm volatile("s_waitcnt vmcnt(0)" ::: "memory"); \
    if (DO_W) DSWRITES(BN); \
    if (DO_I) GLOADS((G) + 2); \
    COMPUTE(BC); \
}

#define EPILOG(JB, ZERO) { \
    const int vt_ = vtg * 4 + (JB); \
    const int gcb = vt_ * 256 + wc * 64 + l31; \
    const float bj0 = bp[(size_t)n * V_ + gcb]; \
    const float bj1 = bp[(size_t)n * V_ + gcb + 32]; \
    _Pragma("unroll") for (int i = 0; i < 4; ++i) { \
        _Pragma("unroll") for (int r = 0; r < 16; ++r) { \
            const int row = mt * 256 + wr * 128 + i * 32 + (r & 3) + 8 * (r >> 2) + 4 * h; \
            float* po = out + (size_t)row * (N_ * V_) + (size_t)n * V_ + gcb; \
            po[0]  = acc[i][0][r] + bj0; \
            po[32] = acc[i][1][r] + bj1; \
        } \
        if (ZERO) { \
            _Pragma("unroll") for (int r = 0; r < 16; ++r) { acc[i][0][r] = 0.f; acc[i][1][r] = 0.f; } \
        } \
    } \
}

__global__ __launch_bounds__(512, 2) void gemmp(const unsigned short* __restrict__ H,
                                                const unsigned short* __restrict__ Wt,
                                                const float* __restrict__ bp,
                                                float* __restrict__ out) {
    extern __shared__ char lds[];
    const int bid = blockIdx.x;
    const int n   = bid & 7;      // XCD k owns n = k
    const int c   = bid >> 3;     // 0..31
    const int mt  = c & 7;        // 0..7
    const int vtg = c >> 3;       // 0..3

    const int t = threadIdx.x;
    const int wid = t >> 6, lane = t & 63;
    const int wr = wid >> 2, wc = wid & 3;
    const int h = lane >> 5, l31 = lane & 31;

    // staging constants: thread t owns granule (r = u*64 + (t>>3), s = t&7)
    const int goff = (t >> 3) * D_ + (t & 7) * 8;   // global element offset
    const int wby  = ((t & 7) * 256 + ((t >> 3) ^ (((t & 7) & 3) << 3))) * 16;

    // read constants: frag (i,kk): plane s = 2kk+h, row-window permuted by m(s)
    int CAb[4], CBb[4];
#pragma unroll
    for (int kk = 0; kk < 4; ++kk) {
        const int sA = 2 * kk + h;
        const int lx = l31 ^ ((sA & 3) << 3);
        CAb[kk] = (sA * 256 + wr * 128 + lx) * 16;
        CBb[kk] = (sA * 256 + wc * 64 + lx) * 16 + 32768;
    }

    const unsigned short* Abase = H  + ((size_t)n * B_ + (size_t)mt * 256) * D_ + goff;
    const unsigned short* Bb0   = Wt + ((size_t)n * V_ + (size_t)vtg * 1024) * D_ + goff;

    f32x16 acc[4][2];
#pragma unroll
    for (int i = 0; i < 4; ++i)
#pragma unroll
        for (int r = 0; r < 16; ++r) { acc[i][0][r] = 0.f; acc[i][1][r] = 0.f; }

    float4 ra0, ra1, ra2, ra3, rb0, rb1, rb2, rb3;

    // prologue: tile 0 -> buf0; tile 1 in flight
    GLOADS(0);
    asm volatile("s_waitcnt vmcnt(0)" ::: "memory");
    DSWRITES(0);
    GLOADS(1);

#pragma unroll 1
    for (int gp = 0; gp < 31; ++gp) {
        const int g = gp * 2;
        STEP(0,     65536, g,     1, 1);
        STEP(65536, 0,     g + 1, 1, 1);
        if ((gp & 7) == 7) { EPILOG(gp >> 3, 1); }
    }
    STEP(0,     65536, 62, 1, 0);   // compute 62, write tile 63, no new loads
    STEP(65536, 0,     63, 0, 0);   // compute 63
    EPILOG(3, 0);
}

// ---------------------------------------------------------------------------
extern "C" void kernel_launch(void* const* d_in, const int* in_sizes, int n_in,
                              void* d_out, int out_size, void* d_ws, size_t ws_size,
                              hipStream_t stream) {
    const float* ie  = (const float*)d_in[0];
    const int*   fts = (const int*)d_in[1];
    const float* emb = (const float*)d_in[2];
    const float* W   = (const float*)d_in[3];
    const float* bp  = (const float*)d_in[4];
    const float* gam = (const float*)d_in[5];
    const float* bet = (const float*)d_in[6];
    float* out = (float*)d_out;

    unsigned short* Wt = (unsigned short*)d_ws;                                     // 64 MiB
    unsigned short* H  = (unsigned short*)((char*)d_ws + (size_t)N_ * V_ * D_ * 2); // +32 MiB

    (void)hipFuncSetAttribute(reinterpret_cast<const void*>(gemmp),
                              hipFuncAttributeMaxDynamicSharedMemorySize, 131072);

    prep<<<dim3(2048 + 8192), dim3(256), 0, stream>>>(ie, fts, emb, gam, bet, W, H, Wt);
    gemmp<<<dim3(256), dim3(512), 131072, stream>>>(H, Wt, bp, out);
}

// Round 7
// 232.427 us; speedup vs baseline: 1.2933x; 1.2933x over previous
//
#include <hip/hip_runtime.h>
#include <hip/hip_bf16.h>

#define B_ 2048
#define N_ 8
#define D_ 1024
#define V_ 4096
#define LN_EPS_ 1e-5f

typedef __bf16 bf16x8 __attribute__((ext_vector_type(8)));
typedef float f32x4 __attribute__((ext_vector_type(4)));

#define GLB(p) ((const __attribute__((address_space(1))) void*)(p))
#define LDSP(p) ((__attribute__((address_space(3))) void*)(p))

static __device__ __forceinline__ unsigned short f2bf(float x) {
    union { float f; unsigned int u; } v;
    v.f = x;
    unsigned int r = v.u + 0x7fffu + ((v.u >> 16) & 1u);
    return (unsigned short)(r >> 16);
}

// ---------------------------------------------------------------------------
// prep: fused  (a) W_pred (N,D,V) f32 -> Wt (N,V,D) bf16   [blocks 2048..10239]
//              (b) gather+cumsum+LN+GELU -> H (N,B,D) bf16 [blocks 0..2047]
// ---------------------------------------------------------------------------
__global__ __launch_bounds__(256) void prep(const float* __restrict__ ie,
                                            const int* __restrict__ feats,
                                            const float* __restrict__ emb,
                                            const float* __restrict__ gamma,
                                            const float* __restrict__ beta,
                                            const float* __restrict__ W,
                                            unsigned short* __restrict__ H,
                                            unsigned short* __restrict__ Wt) {
    const int bid = blockIdx.x;
    const int t = threadIdx.x;

    if (bid >= 2048) {
        __shared__ unsigned short tile[64][65];
        const int w  = bid - 2048;
        const int v0 = (w & 63) * 64;
        const int d0 = ((w >> 6) & 15) * 64;
        const int n  = w >> 10;
        const int tx = t & 15, ty = t >> 4;
#pragma unroll
        for (int i = 0; i < 4; ++i) {
            const int d = ty + i * 16;
            const float4 w4 = *(const float4*)&W[((size_t)n * D_ + d0 + d) * V_ + v0 + tx * 4];
            tile[d][tx * 4 + 0] = f2bf(w4.x);
            tile[d][tx * 4 + 1] = f2bf(w4.y);
            tile[d][tx * 4 + 2] = f2bf(w4.z);
            tile[d][tx * 4 + 3] = f2bf(w4.w);
        }
        __syncthreads();
#pragma unroll
        for (int i = 0; i < 4; ++i) {
            const int v = ty + i * 16;
            ushort4 pk;
            pk.x = tile[tx * 4 + 0][v];
            pk.y = tile[tx * 4 + 1][v];
            pk.z = tile[tx * 4 + 2][v];
            pk.w = tile[tx * 4 + 3][v];
            *reinterpret_cast<ushort4*>(&Wt[((size_t)n * V_ + v0 + v) * D_ + d0 + tx * 4]) = pk;
        }
    } else {
        __shared__ float redS[4], redQ[4];
        const int b = bid;
        const int d0 = t * 4;
        const int lane = t & 63, wid = t >> 6;

        float4 s  = *(const float4*)&ie[(size_t)b * D_ + d0];
        const float4 g4 = *(const float4*)&gamma[d0];
        const float4 be4 = *(const float4*)&beta[d0];

        int fc[N_];
#pragma unroll
        for (int n = 0; n < N_; ++n) fc[n] = feats[b * N_ + n];

#pragma unroll
        for (int n = 0; n < N_; ++n) {
            float ls = s.x + s.y + s.z + s.w;
            float lq = s.x * s.x + s.y * s.y + s.z * s.z + s.w * s.w;
#pragma unroll
            for (int off = 32; off > 0; off >>= 1) {
                ls += __shfl_down(ls, off, 64);
                lq += __shfl_down(lq, off, 64);
            }
            if (lane == 0) { redS[wid] = ls; redQ[wid] = lq; }
            __syncthreads();
            const float tot  = redS[0] + redS[1] + redS[2] + redS[3];
            const float totq = redQ[0] + redQ[1] + redQ[2] + redQ[3];
            __syncthreads();

            const float mu   = tot * (1.0f / D_);
            const float var  = totq * (1.0f / D_) - mu * mu;
            const float rstd = rsqrtf(var + LN_EPS_);

            float h0 = (s.x - mu) * rstd * g4.x + be4.x;
            float h1 = (s.y - mu) * rstd * g4.y + be4.y;
            float h2 = (s.z - mu) * rstd * g4.z + be4.z;
            float h3 = (s.w - mu) * rstd * g4.w + be4.w;
            h0 = 0.5f * h0 * (1.0f + erff(h0 * 0.70710678f));
            h1 = 0.5f * h1 * (1.0f + erff(h1 * 0.70710678f));
            h2 = 0.5f * h2 * (1.0f + erff(h2 * 0.70710678f));
            h3 = 0.5f * h3 * (1.0f + erff(h3 * 0.70710678f));

            ushort4 pk;
            pk.x = f2bf(h0); pk.y = f2bf(h1); pk.z = f2bf(h2); pk.w = f2bf(h3);
            *reinterpret_cast<ushort4*>(&H[((size_t)n * B_ + b) * D_ + d0]) = pk;

            const float4 e = *(const float4*)&emb[((size_t)n * V_ + fc[n]) * (size_t)D_ + d0];
            s.x += e.x; s.y += e.y; s.z += e.z; s.w += e.w;
        }
    }
}

// ---------------------------------------------------------------------------
// gemm8: R2's proven 256x256xBK64 8-wave 4-phase kernel + SECOND BARRIER per
// phase (m201/m218b template cadence: barrier -> reads/stage -> MFMA ->
// barrier), which phase-locks waves so s_setprio arbitration pays (T5).
// All layouts, swizzle, vmcnt counts identical to R2 (verified, 0 conflicts).
// ---------------------------------------------------------------------------
#define MF(a, b, c) __builtin_amdgcn_mfma_f32_16x16x32_bf16((a), (b), (c), 0, 0, 0)

#define STG_A(u, kt, bb) __builtin_amdgcn_global_load_lds( \
    GLB(Ab + (size_t)((u) * 64 + srow) * D_ + (kt) + gsl), \
    LDSP(lds + (bb) + (u) * 8192 + t * 16), 16, 0, 0)
#define STG_B(u, kt, bb) __builtin_amdgcn_global_load_lds( \
    GLB(Bb + (size_t)((u) * 64 + srow) * D_ + (kt) + gsl), \
    LDSP(lds + (bb) + 32768 + (u) * 8192 + t * 16), 16, 0, 0)

#define RD_A(i, ks, bb) (*(const bf16x8*)(lds + (bb) + ((i) >> 1) * 8192 + \
    (((i) & 1) * 32 + wr * 16 + lrow) * 128 + ((((ks) * 4 + lkq) ^ sw) * 16)))
#define RD_B(j, ks, bb) (*(const bf16x8*)(lds + (bb) + 32768 + wc * 8192 + \
    ((j) * 16 + lrow) * 128 + ((((ks) * 4 + lkq) ^ sw) * 16)))

#define QUADP(i0, i1) \
    _Pragma("unroll") for (int j = 0; j < 4; ++j) { \
        acc[i0][j] = MF(A00, Bf[j][0], acc[i0][j]); \
        acc[i0][j] = MF(A01, Bf[j][1], acc[i0][j]); \
        acc[i1][j] = MF(A10, Bf[j][0], acc[i1][j]); \
        acc[i1][j] = MF(A11, Bf[j][1], acc[i1][j]); \
    }

#define TILE(KT, bc, bn) { \
    bf16x8 Bf[4][2]; \
    asm volatile("s_waitcnt vmcnt(3)" ::: "memory"); \
    __builtin_amdgcn_s_barrier(); \
    _Pragma("unroll") for (int j = 0; j < 4; ++j) { Bf[j][0] = RD_B(j, 0, bc); Bf[j][1] = RD_B(j, 1, bc); } \
    { bf16x8 A00 = RD_A(0, 0, bc), A01 = RD_A(0, 1, bc), A10 = RD_A(1, 0, bc), A11 = RD_A(1, 1, bc); \
      STG_B(0, (KT) + 64, bn); STG_B(1, (KT) + 64, bn); \
      __builtin_amdgcn_s_setprio(1); QUADP(0, 1); __builtin_amdgcn_s_setprio(0); } \
    __builtin_amdgcn_s_barrier(); \
    asm volatile("s_waitcnt vmcnt(4)" ::: "memory"); \
    __builtin_amdgcn_s_barrier(); \
    { bf16x8 A00 = RD_A(2, 0, bc), A01 = RD_A(2, 1, bc), A10 = RD_A(3, 0, bc), A11 = RD_A(3, 1, bc); \
      STG_B(2, (KT) + 64, bn); STG_B(3, (KT) + 64, bn); \
      __builtin_amdgcn_s_setprio(1); QUADP(2, 3); __builtin_amdgcn_s_setprio(0); } \
    __builtin_amdgcn_s_barrier(); \
    asm volatile("s_waitcnt vmcnt(4)" ::: "memory"); \
    __builtin_amdgcn_s_barrier(); \
    { bf16x8 A00 = RD_A(4, 0, bc), A01 = RD_A(4, 1, bc), A10 = RD_A(5, 0, bc), A11 = RD_A(5, 1, bc); \
      STG_A(0, (KT) + 64, bn); STG_A(1, (KT) + 64, bn); \
      __builtin_amdgcn_s_setprio(1); QUADP(4, 5); __builtin_amdgcn_s_setprio(0); } \
    __builtin_amdgcn_s_barrier(); \
    asm volatile("s_waitcnt vmcnt(6)" ::: "memory"); \
    __builtin_amdgcn_s_barrier(); \
    { bf16x8 A00 = RD_A(6, 0, bc), A01 = RD_A(6, 1, bc), A10 = RD_A(7, 0, bc), A11 = RD_A(7, 1, bc); \
      STG_A(2, (KT) + 64, bn); STG_A(3, (KT) + 64, bn); \
      __builtin_amdgcn_s_setprio(1); QUADP(6, 7); __builtin_amdgcn_s_setprio(0); } \
    __builtin_amdgcn_s_barrier(); \
}

#define TILE_LAST(bc) { \
    bf16x8 Bf[4][2]; \
    asm volatile("s_waitcnt vmcnt(3)" ::: "memory"); \
    __builtin_amdgcn_s_barrier(); \
    _Pragma("unroll") for (int j = 0; j < 4; ++j) { Bf[j][0] = RD_B(j, 0, bc); Bf[j][1] = RD_B(j, 1, bc); } \
    { bf16x8 A00 = RD_A(0, 0, bc), A01 = RD_A(0, 1, bc), A10 = RD_A(1, 0, bc), A11 = RD_A(1, 1, bc); \
      __builtin_amdgcn_s_setprio(1); QUADP(0, 1); __builtin_amdgcn_s_setprio(0); } \
    __builtin_amdgcn_s_barrier(); \
    asm volatile("s_waitcnt vmcnt(2)" ::: "memory"); \
    __builtin_amdgcn_s_barrier(); \
    { bf16x8 A00 = RD_A(2, 0, bc), A01 = RD_A(2, 1, bc), A10 = RD_A(3, 0, bc), A11 = RD_A(3, 1, bc); \
      __builtin_amdgcn_s_setprio(1); QUADP(2, 3); __builtin_amdgcn_s_setprio(0); } \
    __builtin_amdgcn_s_barrier(); \
    asm volatile("s_waitcnt vmcnt(1)" ::: "memory"); \
    __builtin_amdgcn_s_barrier(); \
    { bf16x8 A00 = RD_A(4, 0, bc), A01 = RD_A(4, 1, bc), A10 = RD_A(5, 0, bc), A11 = RD_A(5, 1, bc); \
      __builtin_amdgcn_s_setprio(1); QUADP(4, 5); __builtin_amdgcn_s_setprio(0); } \
    __builtin_amdgcn_s_barrier(); \
    asm volatile("s_waitcnt vmcnt(0)" ::: "memory"); \
    __builtin_amdgcn_s_barrier(); \
    { bf16x8 A00 = RD_A(6, 0, bc), A01 = RD_A(6, 1, bc), A10 = RD_A(7, 0, bc), A11 = RD_A(7, 1, bc); \
      __builtin_amdgcn_s_setprio(1); QUADP(6, 7); __builtin_amdgcn_s_setprio(0); } \
}

__global__ __launch_bounds__(512, 2) void gemm8(const unsigned short* __restrict__ H,
                                                const unsigned short* __restrict__ Wt,
                                                const float* __restrict__ bp,
                                                float* __restrict__ out) {
    extern __shared__ char lds[];
    const int vt = blockIdx.x, mt = blockIdx.y, n = blockIdx.z;
    const int t = threadIdx.x;
    const int wid = t >> 6, lane = t & 63;
    const int wr = wid >> 2, wc = wid & 3;

    const unsigned short* Ab = H  + ((size_t)n * B_ + (size_t)mt * 256) * D_;
    const unsigned short* Bb = Wt + ((size_t)n * V_ + (size_t)vt * 256) * D_;

    const int srow = t >> 3;
    const int gsl  = ((t & 7) ^ (srow & 7)) * 8;
    const int lrow = lane & 15;
    const int lkq  = lane >> 4;
    const int sw   = lane & 7;

    // bias (oldest VMEM ops; fully drained before the pipeline starts)
    const int col = lane & 15;
    float bias[4];
#pragma unroll
    for (int j = 0; j < 4; ++j)
        bias[j] = bp[(size_t)n * V_ + vt * 256 + wc * 64 + j * 16 + col];
    asm volatile("s_waitcnt vmcnt(0)" ::: "memory");
    __builtin_amdgcn_sched_barrier(0);

    f32x4 acc[8][4] = {};

    // prologue: stage tile 0 into buf0 (B0 B1 B2 B3 A0 A1 A2 A3)
    STG_B(0, 0, 0); STG_B(1, 0, 0); STG_B(2, 0, 0); STG_B(3, 0, 0);
    STG_A(0, 0, 0); STG_A(1, 0, 0); STG_A(2, 0, 0); STG_A(3, 0, 0);

    int kt = 0;
#pragma unroll 1
    for (int it = 0; it < 7; ++it) {       // tiles 0..13
        TILE(kt, 0, 65536); kt += 64;
        TILE(kt, 65536, 0); kt += 64;
    }
    TILE(kt, 0, 65536);                    // tile 14 (stages tile 15)
    TILE_LAST(65536);                      // tile 15

    // epilogue: C/D layout col = lane&15, row = (lane>>4)*4 + reg
    const int rg  = (lane >> 4) * 4;
    const int gc0 = vt * 256 + wc * 64 + col;
#pragma unroll
    for (int i = 0; i < 8; ++i) {
        const int row = mt * 256 + i * 32 + wr * 16 + rg;
#pragma unroll
        for (int j = 0; j < 4; ++j) {
            const int gcol = gc0 + j * 16;
#pragma unroll
            for (int r = 0; r < 4; ++r) {
                out[((size_t)(row + r) * N_ + n) * V_ + gcol] = acc[i][j][r] + bias[j];
            }
        }
    }
}

// ---------------------------------------------------------------------------
extern "C" void kernel_launch(void* const* d_in, const int* in_sizes, int n_in,
                              void* d_out, int out_size, void* d_ws, size_t ws_size,
                              hipStream_t stream) {
    const float* ie  = (const float*)d_in[0];
    const int*   fts = (const int*)d_in[1];
    const float* emb = (const float*)d_in[2];
    const float* W   = (const float*)d_in[3];
    const float* bp  = (const float*)d_in[4];
    const float* gam = (const float*)d_in[5];
    const float* bet = (const float*)d_in[6];
    float* out = (float*)d_out;

    unsigned short* Wt = (unsigned short*)d_ws;                                     // 64 MiB
    unsigned short* H  = (unsigned short*)((char*)d_ws + (size_t)N_ * V_ * D_ * 2); // +32 MiB

    (void)hipFuncSetAttribute(reinterpret_cast<const void*>(gemm8),
                              hipFuncAttributeMaxDynamicSharedMemorySize, 131072);

    prep<<<dim3(2048 + 8192), dim3(256), 0, stream>>>(ie, fts, emb, gam, bet, W, H, Wt);
    gemm8<<<dim3(V_ / 256, B_ / 256, N_), dim3(512), 131072, stream>>>(H, Wt, bp, out);
}